// Round 3
// baseline (332.208 us; speedup 1.0000x reference)
//
#include <hip/hip_runtime.h>

// LIF recurrence: T timesteps, BN independent neurons.
// mem_{t+1} = (0.5*mem_t + syn_t) * (1 - out_t); syn_{t+1} = in[t]; out_t = mem_t > 1.
// Memory-bound: 210 MB read + 210 MB write, floor ~67 us at 6.3 TB/s achievable.
//
// Round 2 -> 3 change: prefetch distance 2 -> 8.
// Loads and stores SHARE vmcnt on CDNA. At distance 2, the consume waits at
// vmcnt(~4) counting pending stores too -> ~2 VM ops in flight -> Little's law
// caps the wave at ~0.5 KB/900cyc -> ~1.2 TB/s chip-wide (matches measurement).
// At distance 8 the consume waits at vmcnt(~16): 8 loads always in flight
// (16 waves/CU x 8 x 512 B = 64 KB outstanding reads/CU -> ~72 B/cyc/CU,
// comfortably above the 10.25 B/cyc/CU needed for 6.3 TB/s).

constexpr int T_STEPS = 100;
constexpr int PF = 8;  // prefetch distance

typedef float v2f __attribute__((ext_vector_type(2)));

__global__ __launch_bounds__(256) void lif_kernel(const v2f* __restrict__ in,
                                                  v2f* __restrict__ out,
                                                  int bn2) {
    const int i = blockIdx.x * blockDim.x + threadIdx.x;
    if (i >= bn2) return;

    const v2f* __restrict__ ip = in + i;
    v2f* __restrict__ op = out + i;

    v2f mem = 0.0f;
    v2f syn = 0.0f;

    // Prime the 8-deep pipeline: h_0 .. h_7 in flight.
    v2f hP[PF];
#pragma unroll
    for (int k = 0; k < PF; ++k) {
        hP[k] = __builtin_nontemporal_load(ip + (long)k * bn2);
    }

#pragma unroll
    for (int t = 0; t < T_STEPS; ++t) {
        // Issue load for t+PF before consuming h_t — keeps PF loads outstanding.
        v2f hn = 0.0f;
        if (t + PF < T_STEPS) {
            hn = __builtin_nontemporal_load(ip + (long)(t + PF) * bn2);
        }

        v2f o;
        o.x = mem.x > 1.0f ? 1.0f : 0.0f;
        o.y = mem.y > 1.0f ? 1.0f : 0.0f;

        __builtin_nontemporal_store(o, op + (long)t * bn2);

        // detach_reset: zero where spiked, else leaky integrate with delayed syn.
        mem.x = (o.x != 0.0f) ? 0.0f : fmaf(0.5f, mem.x, syn.x);
        mem.y = (o.y != 0.0f) ? 0.0f : fmaf(0.5f, mem.y, syn.y);

        const int idx = t % PF;        // static after full unroll
        syn = hP[idx];                  // syn_{t+1} = in[t]
        hP[idx] = hn;
    }
}

extern "C" void kernel_launch(void* const* d_in, const int* in_sizes, int n_in,
                              void* d_out, int out_size, void* d_ws, size_t ws_size,
                              hipStream_t stream) {
    const float* in = (const float*)d_in[0];
    float* out = (float*)d_out;

    const int total = in_sizes[0];          // T * B * N
    const int bn = total / T_STEPS;         // B * N = 524288
    const int bn2 = bn / 2;                 // float2 columns per timestep = 262144

    const int block = 256;
    const int grid = (bn2 + block - 1) / block;  // 1024 blocks

    lif_kernel<<<grid, block, 0, stream>>>((const v2f*)in, (v2f*)out, bn2);
}